// Round 1
// baseline (479.710 us; speedup 1.0000x reference)
//
#include <hip/hip_runtime.h>

// EmbeddingToExpression: out[a,b] = sigmoid(E[a,b,:] @ W1[rix[b]] + b1[rix[b]]) @ W2[rix[b]] + b2[rix[b]]
// A = 4096 cells, B = 4096 regions_b, NE = 5, NI = 5.
// Memory-bound: 335 MB E read + 67 MB out write => ~64 us floor at 6.3 TB/s.
//
// R1: stage E through LDS with coalesced float4 loads (direct stride-20B reads -> 0.84 TB/s).
// R2 (this round):
//   (a) software-pipeline staging: prefetch chunk k+1 into registers while computing
//       chunk k — removes barrier-serialized HBM latency exposure per chunk.
//   (b) sigmoid via __builtin_amdgcn_rcpf (v_rcp_f32) instead of full-precision divide
//       (~12-op div sequence x5 per output; tolerance is 2^-8, rcp is ~1 ulp).
//   (c) pre-pack per-column params into SoA pk[36][4096] in d_ws with a 16-block
//       pre-kernel — main kernel param loads become fully coalesced; removes the
//       36-instr fully-divergent gather that every one of the 128 grid.y blocks
//       redundantly repeated. Falls back to in-kernel gather if ws too small.

#define NA 4096
#define NB 4096
#define NE 5
#define NI 5
#define NPAR 36                 // 25 W1 + 5 B1 + 5 W2 + 1 B2
#define ROWS 32                 // rows of 'a' per block
#define SROWS 4                 // rows staged per chunk (one wave per row)
#define ROW_FLOATS (256 * NE)   // 1280 floats per (row, 256-col) slice
#define NCHUNK (ROWS / SROWS)

__global__ __launch_bounds__(256) void pack_params(
    const int*   __restrict__ rix,
    const float* __restrict__ w1,
    const float* __restrict__ b1,
    const float* __restrict__ w2,
    const float* __restrict__ b2,
    float*       __restrict__ pk)   // [NPAR, NB] SoA
{
    const int b = blockIdx.x * 256 + threadIdx.x;
    const int r = rix[b];
    const float* w1p = w1 + (size_t)r * (NE * NI);
    const float* b1p = b1 + (size_t)r * NI;
    const float* w2p = w2 + (size_t)r * NI;
#pragma unroll
    for (int j = 0; j < NE * NI; ++j)
        pk[(size_t)j * NB + b] = w1p[j];
#pragma unroll
    for (int d = 0; d < NI; ++d) {
        pk[(size_t)(25 + d) * NB + b] = b1p[d];
        pk[(size_t)(30 + d) * NB + b] = w2p[d];
    }
    pk[(size_t)35 * NB + b] = b2[r];
}

template <bool PK>
__global__ __launch_bounds__(256) void e2e_kernel(
    const float* __restrict__ E,     // [NA, NB, NE]
    const float* __restrict__ pk,    // [NPAR, NB] (PK path)
    const int*   __restrict__ rix,   // fallback path
    const float* __restrict__ w1,
    const float* __restrict__ b1,
    const float* __restrict__ w2,
    const float* __restrict__ b2,
    float*       __restrict__ out)   // [NA, NB]
{
    __shared__ float lds[SROWS * ROW_FLOATS];   // 20 KB

    const int tid  = threadIdx.x;
    const int b0   = blockIdx.x * 256;
    const int b    = b0 + tid;
    const int a0   = blockIdx.y * ROWS;
    const int srow = tid >> 6;                  // 0..3: which staged row this wave loads
    const int lane = tid & 63;

    // Prologue: get the first chunk's E loads in flight immediately.
    float4 pf0, pf1, pf2, pf3, pf4;
    {
        const float4* src = (const float4*)(E + (((size_t)a0 + srow) * NB + b0) * NE);
        pf0 = src[lane];
        pf1 = src[lane + 64];
        pf2 = src[lane + 128];
        pf3 = src[lane + 192];
        pf4 = src[lane + 256];
    }

    // Per-column params -> registers (36 floats).
    float P[NPAR];
    if (PK) {
        // fully coalesced: lane stride 4 B per load, table is L2-resident (576 KB)
#pragma unroll
        for (int j = 0; j < NPAR; ++j)
            P[j] = pk[(size_t)j * NB + b];
    } else {
        const int r = rix[b];
        const float* w1p = w1 + (size_t)r * (NE * NI);
        const float* b1p = b1 + (size_t)r * NI;
        const float* w2p = w2 + (size_t)r * NI;
#pragma unroll
        for (int j = 0; j < NE * NI; ++j) P[j] = w1p[j];
#pragma unroll
        for (int d = 0; d < NI; ++d) { P[25 + d] = b1p[d]; P[30 + d] = w2p[d]; }
        P[35] = b2[r];
    }

#pragma unroll 1
    for (int chunk = 0; chunk < NCHUNK; ++chunk) {
        // ---- write prefetched chunk to LDS (coalesced float4, conflict-free) ----
        float4* dst = (float4*)(lds + srow * ROW_FLOATS);
        dst[lane]       = pf0;
        dst[lane + 64]  = pf1;
        dst[lane + 128] = pf2;
        dst[lane + 192] = pf3;
        dst[lane + 256] = pf4;
        __syncthreads();

        // ---- issue next chunk's global loads; they fly during compute below ----
        if (chunk + 1 < NCHUNK) {
            const float4* src = (const float4*)(
                E + (((size_t)a0 + (chunk + 1) * SROWS + srow) * NB + b0) * NE);
            pf0 = src[lane];
            pf1 = src[lane + 64];
            pf2 = src[lane + 128];
            pf3 = src[lane + 192];
            pf4 = src[lane + 256];
        }

        // ---- compute SROWS outputs for this thread's column ----
        // LDS read at stride 5 dwords: gcd(5,32)=1 -> 2 lanes/bank = free.
#pragma unroll
        for (int s = 0; s < SROWS; ++s) {
            const float* e = lds + s * ROW_FLOATS + tid * NE;
            const float e0 = e[0], e1 = e[1], e2 = e[2], e3 = e[3], e4 = e[4];

            float acc = P[35];
#pragma unroll
            for (int d = 0; d < NI; ++d) {
                float h = P[25 + d]
                        + e0 * P[d]
                        + e1 * P[5 + d]
                        + e2 * P[10 + d]
                        + e3 * P[15 + d]
                        + e4 * P[20 + d];
                const float sg = __builtin_amdgcn_rcpf(1.0f + __expf(-h));
                acc = fmaf(sg, P[30 + d], acc);
            }
            out[((size_t)(a0 + chunk * SROWS + s)) * NB + b] = acc;
        }

        __syncthreads();   // protect LDS before next chunk's ds_write
    }
}

extern "C" void kernel_launch(void* const* d_in, const int* in_sizes, int n_in,
                              void* d_out, int out_size, void* d_ws, size_t ws_size,
                              hipStream_t stream) {
    const float* E   = (const float*)d_in[0];
    const int*   rix = (const int*)  d_in[1];
    const float* w1  = (const float*)d_in[2];
    const float* b1  = (const float*)d_in[3];
    const float* w2  = (const float*)d_in[4];
    const float* b2  = (const float*)d_in[5];
    float*       out = (float*)d_out;

    dim3 grid(NB / 256, NA / ROWS);   // 16 x 128 = 2048 blocks
    dim3 block(256);

    const size_t pk_bytes = (size_t)NPAR * NB * sizeof(float);   // 576 KB
    if (d_ws != nullptr && ws_size >= pk_bytes) {
        float* pk = (float*)d_ws;
        hipLaunchKernelGGL(pack_params, dim3(NB / 256), block, 0, stream,
                           rix, w1, b1, w2, b2, pk);
        hipLaunchKernelGGL((e2e_kernel<true>), grid, block, 0, stream,
                           E, pk, rix, w1, b1, w2, b2, out);
    } else {
        hipLaunchKernelGGL((e2e_kernel<false>), grid, block, 0, stream,
                           E, nullptr, rix, w1, b1, w2, b2, out);
    }
}